// Round 5
// baseline (179.739 us; speedup 1.0000x reference)
//
#include <hip/hip_runtime.h>

#define AS_GLOBAL __attribute__((address_space(1)))
#define AS_LDS    __attribute__((address_space(3)))

typedef __bf16 bf16;
typedef __bf16 bf16x8 __attribute__((ext_vector_type(8)));
typedef float  f32x4  __attribute__((ext_vector_type(4)));

__device__ __forceinline__ void gload16(const void* g, void* l) {
  __builtin_amdgcn_global_load_lds((const AS_GLOBAL unsigned int*)g,
                                   (AS_LDS unsigned int*)l, 16, 0, 0);
}

// swizzled LDS address for a [R][128B] row-major tile:
// stored_byte = row*128 + (bytecol ^ ((row&7)<<4))
__device__ __forceinline__ void* swz(void* base, int row, int bytecol) {
  return (char*)base + row * 128 + (bytecol ^ ((row & 7) << 4));
}

// ---------------- prep kernels ----------------

__global__ __launch_bounds__(256) void k_cvt_bf16(const float* __restrict__ x,
                                                  bf16* __restrict__ o, int n8) {
  int i = blockIdx.x * blockDim.x + threadIdx.x;
  if (i >= n8) return;
  const float4* p = (const float4*)(x + (size_t)i * 8);
  float4 a = p[0], b = p[1];
  bf16x8 v;
  v[0] = (bf16)a.x; v[1] = (bf16)a.y; v[2] = (bf16)a.z; v[3] = (bf16)a.w;
  v[4] = (bf16)b.x; v[5] = (bf16)b.y; v[6] = (bf16)b.z; v[7] = (bf16)b.w;
  *(bf16x8*)(o + (size_t)i * 8) = v;
}

// W [K=1024][N=1024] fp32 (in,out) -> WT [N][K] bf16
__global__ __launch_bounds__(256) void k_wt(const float* __restrict__ W,
                                            bf16* __restrict__ WT) {
  int lin = blockIdx.x * blockDim.x + threadIdx.x;
  int n  = lin & 1023;
  int kc = lin >> 10;
  bf16x8 v;
#pragma unroll
  for (int j = 0; j < 8; ++j) v[j] = (bf16)W[(size_t)(kc * 8 + j) * 1024 + n];
  *(bf16x8*)&WT[(size_t)n * 1024 + kc * 8] = v;
}

__global__ __launch_bounds__(256) void k_bcat(const float* __restrict__ bq,
                                              const float* __restrict__ bk,
                                              const float* __restrict__ bv,
                                              float* __restrict__ bc) {
  int i = blockIdx.x * blockDim.x + threadIdx.x;
  if (i < 1024) bc[i] = bq[i];
  else if (i < 2048) bc[i] = bk[i - 1024];
  else if (i < 3072) bc[i] = bv[i - 2048];
}

// V region of qkv [4096][3072] -> Vt [b][h][d=64][t=2048] bf16
__global__ __launch_bounds__(256) void k_transpose_v(const bf16* __restrict__ qkv,
                                                     bf16* __restrict__ vt) {
  int blk = blockIdx.x;
  int tc = blk & 63, h = (blk >> 6) & 15, b = blk >> 10;
  int d = threadIdx.x & 63, tq = threadIdx.x >> 6;
  int t0 = tc * 32 + tq * 8;
  bf16x8 v;
#pragma unroll
  for (int j = 0; j < 8; ++j)
    v[j] = qkv[(size_t)(b * 2048 + t0 + j) * 3072 + 2048 + h * 64 + d];
  *(bf16x8*)&vt[((size_t)(b * 16 + h) * 64 + d) * 2048 + t0] = v;
}

// ---------------- GEMM: C[M,N] = A[M,K] @ Bt[N,K]^T + bias ----------------
// XCD-chunked block swizzle: total blocks % 8 == 0 in all our launches.
template <typename OutT>
__global__ __launch_bounds__(256) void k_gemm_bt(const bf16* __restrict__ A,
                                                 const bf16* __restrict__ Bt,
                                                 const float* __restrict__ bias,
                                                 OutT* __restrict__ C,
                                                 int K, int N) {
  __shared__ bf16 As[128 * 32];
  __shared__ bf16 Bs[128 * 32];
  const int tid = threadIdx.x;
  const int w = tid >> 6, l = tid & 63, g = l >> 4, c = l & 15;
  const int wr = w >> 1, wc = w & 1;
  // XCD-aware chunked remap (perf heuristic only; bijective since total%8==0)
  int lin = blockIdx.y * gridDim.x + blockIdx.x;
  int chunk = (gridDim.x * gridDim.y) >> 3;
  int nl = (lin & 7) * chunk + (lin >> 3);
  const int row0 = (nl % gridDim.x) * 128, col0 = (nl / gridDim.x) * 128;
  f32x4 acc[4][4] = {};

  for (int k0 = 0; k0 < K; k0 += 32) {
#pragma unroll
    for (int it = 0; it < 2; ++it) {
      int idx = it * 256 + tid;
      int r = idx >> 2, cc = idx & 3;
      gload16(A  + (size_t)(row0 + r) * K + k0 + cc * 8, &As[idx * 8]);
      gload16(Bt + (size_t)(col0 + r) * K + k0 + cc * 8, &Bs[idx * 8]);
    }
    __syncthreads();
    bf16x8 af[4], bfr[4];
#pragma unroll
    for (int m = 0; m < 4; ++m)
      af[m] = *(const bf16x8*)&As[(wr * 64 + m * 16 + c) * 32 + g * 8];
#pragma unroll
    for (int n = 0; n < 4; ++n)
      bfr[n] = *(const bf16x8*)&Bs[(wc * 64 + n * 16 + c) * 32 + g * 8];
#pragma unroll
    for (int m = 0; m < 4; ++m)
#pragma unroll
      for (int n = 0; n < 4; ++n)
        acc[m][n] = __builtin_amdgcn_mfma_f32_16x16x32_bf16(af[m], bfr[n],
                                                            acc[m][n], 0, 0, 0);
    __syncthreads();
  }

#pragma unroll
  for (int m = 0; m < 4; ++m) {
    int row = row0 + wr * 64 + m * 16 + g * 4;
#pragma unroll
    for (int n = 0; n < 4; ++n) {
      int col = col0 + wc * 64 + n * 16 + c;
      float bv = bias[col];
#pragma unroll
      for (int r = 0; r < 4; ++r) {
        float v = acc[m][n][r] + bv;
        C[(size_t)(row + r) * N + col] = (OutT)v;
      }
    }
  }
}

// ---------------- flash attention v5 --------------------------------------
// 1024 blocks, one q-tile (64 rows) each. 8 waves = 4 q-subtiles x 2 s-halves.
// Wave (wq, wh): 16 q-rows (wq), 32-s half (wh) of each 64-s KV tile.
// End-of-block merge of the two online-softmax partials via LDS.
// 2-buffer KV pipeline, LDS 40KB, one barrier + one vmcnt(0) per tile.
// mask: valid iff s <= q && !(s % 3 == 1 && s >= 4)
__global__ __launch_bounds__(512, 6) void k_attn(const bf16* __restrict__ qkv,
                                                 const bf16* __restrict__ vt,
                                                 bf16* __restrict__ att) {
  const int idx = blockIdx.x;
  const int slot = idx >> 8, j = idx & 255;
  const int r8 = j >> 5, bh = j & 31;
  const int b = bh >> 4, h = bh & 15;
  int qt;
  switch (slot) {
    case 0: qt = r8;       break;
    case 1: qt = 31 - r8;  break;
    case 2: qt = r8 + 8;   break;
    default: qt = 23 - r8; break;
  }

  const int tid = threadIdx.x;
  const int w = tid >> 6, l = tid & 63, g = l >> 4, c = l & 15;
  const int wq = w & 3, wh = w >> 2;        // q-subtile, s-half
  const int qw0 = qt * 64 + wq * 16;
  const int nt = qt + 1;

  __shared__ bf16 Ks[2][64 * 64];    // [s][d] swizzled 128B rows (8KB each)
  __shared__ bf16 Vs[2][64 * 64];    // [d][s] swizzled 128B rows
  __shared__ bf16 Plds[4][16 * 64];  // per wave-PAIR [q][s]; halves disjoint

  const bf16* kg = qkv + (size_t)(b * 2048) * 3072 + 1024 + h * 64;
  const bf16* vg = vt + (size_t)(b * 16 + h) * 64 * 2048;

  // stage KV tile t into buf: 512 threads, 1 K-chunk + 1 V-chunk each
  auto stage = [&](int buf, int t) {
    int s0 = t * 64;
    int rr = tid >> 3, jj = (tid & 7) ^ (rr & 7);
    gload16(kg + (size_t)(s0 + rr) * 3072 + jj * 8, &Ks[buf][tid * 8]);
    gload16(vg + (size_t)rr * 2048 + s0 + jj * 8, &Vs[buf][tid * 8]);
  };

  // Q A-frags, pre-scaled by 1/sqrt(64)=0.125 (exact in bf16)
  const bf16* qb = qkv + (size_t)(b * 2048 + qw0 + c) * 3072 + h * 64 + g * 8;
  bf16x8 qf0 = *(const bf16x8*)qb;
  bf16x8 qf1 = *(const bf16x8*)(qb + 32);
#pragma unroll
  for (int jq = 0; jq < 8; ++jq) {
    qf0[jq] = (bf16)((float)qf0[jq] * 0.125f);
    qf1[jq] = (bf16)((float)qf1[jq] * 0.125f);
  }

  f32x4 o[4] = {};
  float mrow[4] = {-1e30f, -1e30f, -1e30f, -1e30f};
  float ell[4] = {0.f, 0.f, 0.f, 0.f};

  stage(0, 0);

  int cur = 0;
#pragma unroll 1
  for (int t = 0; t < nt; ++t) {
    // only stage(t) in flight here: wait own share, then block-wide visible
    asm volatile("s_waitcnt vmcnt(0)" ::: "memory");
    __builtin_amdgcn_sched_barrier(0);
    __builtin_amdgcn_s_barrier();       // stage(t) complete everywhere;
    __builtin_amdgcn_sched_barrier(0);  // all waves done reading tile t-1

    if (t + 1 < nt) stage(cur ^ 1, t + 1);  // overwrites t-1's buffer: safe

    // ---- S = Q K^T (own 32-s half: rows wh*32 + st*16 + c of K tile) ----
    f32x4 ss[2] = {};
#pragma unroll
    for (int st = 0; st < 2; ++st) {
      int krow = wh * 32 + st * 16 + c;
      bf16x8 ka  = *(const bf16x8*)swz(&Ks[cur][0], krow, g * 16);
      bf16x8 kb2 = *(const bf16x8*)swz(&Ks[cur][0], krow, 64 + g * 16);
      ss[st] = __builtin_amdgcn_mfma_f32_16x16x32_bf16(qf0, ka,  ss[st], 0, 0, 0);
      ss[st] = __builtin_amdgcn_mfma_f32_16x16x32_bf16(qf1, kb2, ss[st], 0, 0, 0);
    }

    // ---- mask (C-layout: row q = g*4+r, col s = t*64 + wh*32 + st*16+c) --
    const int sc = t * 64 + wh * 32 + c;
    const bool diag = (t == qt);
    bool cm[2];
#pragma unroll
    for (int st = 0; st < 2; ++st) {
      int s = sc + st * 16;
      cm[st] = ((s % 3) == 1) && (s >= 4);
    }
    float mx[4];
#pragma unroll
    for (int r = 0; r < 4; ++r) {
      int q = qw0 + g * 4 + r;
      float m = -1e30f;
#pragma unroll
      for (int st = 0; st < 2; ++st) {
        int s = sc + st * 16;
        bool ok = !cm[st] && (!diag || s <= q);
        float v = ok ? ss[st][r] : -1e30f;
        ss[st][r] = v;
        m = fmaxf(m, v);
      }
      mx[r] = m;
    }
    // ---- online softmax (16-lane column groups) ----
#pragma unroll
    for (int r = 0; r < 4; ++r) {
      mx[r] = fmaxf(mx[r], __shfl_xor(mx[r], 1));
      mx[r] = fmaxf(mx[r], __shfl_xor(mx[r], 2));
      mx[r] = fmaxf(mx[r], __shfl_xor(mx[r], 4));
      mx[r] = fmaxf(mx[r], __shfl_xor(mx[r], 8));
    }
    float al[4];
#pragma unroll
    for (int r = 0; r < 4; ++r) {
      float mn = fmaxf(mrow[r], mx[r]);
      al[r] = __expf(mrow[r] - mn);
      mrow[r] = mn;
      float rsum = 0.f;
#pragma unroll
      for (int st = 0; st < 2; ++st) {
        float pv = __expf(ss[st][r] - mn);
        rsum += pv;
        *(bf16*)swz(&Plds[wq][0], g * 4 + r, wh * 64 + st * 32 + c * 2) = (bf16)pv;
      }
      rsum += __shfl_xor(rsum, 1);
      rsum += __shfl_xor(rsum, 2);
      rsum += __shfl_xor(rsum, 4);
      rsum += __shfl_xor(rsum, 8);
      ell[r] = ell[r] * al[r] + rsum;
    }
#pragma unroll
    for (int dc = 0; dc < 4; ++dc)
#pragma unroll
      for (int r = 0; r < 4; ++r) o[dc][r] *= al[r];

    // wave-pair-private P (disjoint swizzled halves): rule #18 fence pair
    asm volatile("s_waitcnt lgkmcnt(0)" ::: "memory");
    __builtin_amdgcn_sched_barrier(0);

    // ---- O += P @ V over own s-half (k = wh*32 + g*8 + j) ----
    {
      bf16x8 pf = *(const bf16x8*)swz(&Plds[wq][0], c, wh * 64 + g * 16);
#pragma unroll
      for (int dc = 0; dc < 4; ++dc) {
        bf16x8 vf = *(const bf16x8*)swz(&Vs[cur][0], dc * 16 + c, wh * 64 + g * 16);
        o[dc] = __builtin_amdgcn_mfma_f32_16x16x32_bf16(pf, vf, o[dc], 0, 0, 0);
      }
    }

    cur ^= 1;
  }

  // ---- cross-half merge via LDS (reuse Ks/Vs storage) ----
  float* mo  = (float*)&Ks[0][0];   // [4][16][64] o-partials (16KB exact)
  float* mml = (float*)&Vs[0][0];   // [4][16][2]  m,l partials

  __syncthreads();                  // everyone done with Ks/Vs + P
  if (wh == 1) {
#pragma unroll
    for (int dc = 0; dc < 4; ++dc)
#pragma unroll
      for (int r = 0; r < 4; ++r)
        mo[(wq * 16 + g * 4 + r) * 64 + dc * 16 + c] = o[dc][r];
    if (c == 0) {
#pragma unroll
      for (int r = 0; r < 4; ++r) {
        mml[(wq * 16 + g * 4 + r) * 2]     = mrow[r];
        mml[(wq * 16 + g * 4 + r) * 2 + 1] = ell[r];
      }
    }
  }
  __syncthreads();
  if (wh == 0) {
#pragma unroll
    for (int r = 0; r < 4; ++r) {
      int row = wq * 16 + g * 4 + r;
      float m2 = mml[row * 2], l2 = mml[row * 2 + 1];
      float mn = fmaxf(mrow[r], m2);
      float a1 = __expf(mrow[r] - mn);
      float a2 = __expf(m2 - mn);           // = 0 when half 2 was all-masked
      float li = 1.f / (ell[r] * a1 + l2 * a2);
      int q = qw0 + g * 4 + r;
#pragma unroll
      for (int dc = 0; dc < 4; ++dc) {
        float o2 = mo[row * 64 + dc * 16 + c];
        att[(size_t)(b * 2048 + q) * 1024 + h * 64 + dc * 16 + c] =
            (bf16)((o[dc][r] * a1 + o2 * a2) * li);
      }
    }
  }
}

// ---------------- launcher ----------------
extern "C" void kernel_launch(void* const* d_in, const int* in_sizes, int n_in,
                              void* d_out, int out_size, void* d_ws, size_t ws_size,
                              hipStream_t stream) {
  const float* x  = (const float*)d_in[0];
  const float* Wq = (const float*)d_in[1];
  const float* bq = (const float*)d_in[2];
  const float* Wk = (const float*)d_in[3];
  const float* bk = (const float*)d_in[4];
  const float* Wv = (const float*)d_in[5];
  const float* bv = (const float*)d_in[6];
  const float* Wp = (const float*)d_in[7];
  const float* bp = (const float*)d_in[8];
  float* out = (float*)d_out;

  char* ws = (char*)d_ws;
  const size_t MB = 1024 * 1024;
  bf16*  xb    = (bf16*)(ws);             // 8 MB [4096][1024]; reused as att
  bf16*  wqkvT = (bf16*)(ws + 8 * MB);    // 6 MB [3072][1024]
  bf16*  wpT   = (bf16*)(ws + 14 * MB);   // 2 MB [1024][1024]
  float* bcat  = (float*)(ws + 16 * MB);  // 12 KB
  bf16*  qkv   = (bf16*)(ws + 17 * MB);   // 24 MB [4096][3072]
  bf16*  vtr   = (bf16*)(ws + 41 * MB);   // 8 MB [2][16][64][2048]
  bf16*  att   = xb;                      // alias: xb dead after QKV GEMM

  k_cvt_bf16<<<2048, 256, 0, stream>>>(x, xb, 524288);
  k_wt<<<512, 256, 0, stream>>>(Wq, wqkvT);
  k_wt<<<512, 256, 0, stream>>>(Wk, wqkvT + 1024 * 1024);
  k_wt<<<512, 256, 0, stream>>>(Wv, wqkvT + 2 * 1024 * 1024);
  k_wt<<<512, 256, 0, stream>>>(Wp, wpT);
  k_bcat<<<12, 256, 0, stream>>>(bq, bk, bv, bcat);

  k_gemm_bt<bf16><<<dim3(32, 24), 256, 0, stream>>>(xb, wqkvT, bcat, qkv, 1024, 3072);
  k_transpose_v<<<2048, 256, 0, stream>>>(qkv, vtr);
  k_attn<<<1024, 512, 0, stream>>>(qkv, vtr, att);
  k_gemm_bt<float><<<dim3(32, 8), 256, 0, stream>>>(att, wpT, bp, out, 1024, 1024);
}

// Round 6
// 146.592 us; speedup vs baseline: 1.2261x; 1.2261x over previous
//
#include <hip/hip_runtime.h>

#define AS_GLOBAL __attribute__((address_space(1)))
#define AS_LDS    __attribute__((address_space(3)))

typedef __bf16 bf16;
typedef __bf16 bf16x4 __attribute__((ext_vector_type(4)));
typedef __bf16 bf16x8 __attribute__((ext_vector_type(8)));
typedef float  f32x4  __attribute__((ext_vector_type(4)));

__device__ __forceinline__ void gload16(const void* g, void* l) {
  __builtin_amdgcn_global_load_lds((const AS_GLOBAL unsigned int*)g,
                                   (AS_LDS unsigned int*)l, 16, 0, 0);
}

// swizzled LDS address for a [R][128B] row-major tile:
// stored_byte = row*128 + (bytecol ^ ((row&7)<<4))
__device__ __forceinline__ void* swz(void* base, int row, int bytecol) {
  return (char*)base + row * 128 + (bytecol ^ ((row & 7) << 4));
}

// ---------------- prep kernels ----------------

__global__ __launch_bounds__(256) void k_cvt_bf16(const float* __restrict__ x,
                                                  bf16* __restrict__ o, int n8) {
  int i = blockIdx.x * blockDim.x + threadIdx.x;
  if (i >= n8) return;
  const float4* p = (const float4*)(x + (size_t)i * 8);
  float4 a = p[0], b = p[1];
  bf16x8 v;
  v[0] = (bf16)a.x; v[1] = (bf16)a.y; v[2] = (bf16)a.z; v[3] = (bf16)a.w;
  v[4] = (bf16)b.x; v[5] = (bf16)b.y; v[6] = (bf16)b.z; v[7] = (bf16)b.w;
  *(bf16x8*)(o + (size_t)i * 8) = v;
}

// W [K=1024][N=1024] fp32 (in,out) -> WT [N][K] bf16
__global__ __launch_bounds__(256) void k_wt(const float* __restrict__ W,
                                            bf16* __restrict__ WT) {
  int lin = blockIdx.x * blockDim.x + threadIdx.x;
  int n  = lin & 1023;
  int kc = lin >> 10;
  bf16x8 v;
#pragma unroll
  for (int j = 0; j < 8; ++j) v[j] = (bf16)W[(size_t)(kc * 8 + j) * 1024 + n];
  *(bf16x8*)&WT[(size_t)n * 1024 + kc * 8] = v;
}

__global__ __launch_bounds__(256) void k_bcat(const float* __restrict__ bq,
                                              const float* __restrict__ bk,
                                              const float* __restrict__ bv,
                                              float* __restrict__ bc) {
  int i = blockIdx.x * blockDim.x + threadIdx.x;
  if (i < 1024) bc[i] = bq[i];
  else if (i < 2048) bc[i] = bk[i - 1024];
  else if (i < 3072) bc[i] = bv[i - 2048];
}

// V region of qkv [4096][3072] -> Vt [b][h][d=64][t=2048] bf16
__global__ __launch_bounds__(256) void k_transpose_v(const bf16* __restrict__ qkv,
                                                     bf16* __restrict__ vt) {
  int blk = blockIdx.x;
  int tc = blk & 63, h = (blk >> 6) & 15, b = blk >> 10;
  int d = threadIdx.x & 63, tq = threadIdx.x >> 6;
  int t0 = tc * 32 + tq * 8;
  bf16x8 v;
#pragma unroll
  for (int j = 0; j < 8; ++j)
    v[j] = qkv[(size_t)(b * 2048 + t0 + j) * 3072 + 2048 + h * 64 + d];
  *(bf16x8*)&vt[((size_t)(b * 16 + h) * 64 + d) * 2048 + t0] = v;
}

// ---------------- GEMM: C[M,N] = A[M,K] @ Bt[N,K]^T + bias ----------------
template <typename OutT>
__global__ __launch_bounds__(256) void k_gemm_bt(const bf16* __restrict__ A,
                                                 const bf16* __restrict__ Bt,
                                                 const float* __restrict__ bias,
                                                 OutT* __restrict__ C,
                                                 int K, int N) {
  __shared__ bf16 As[128 * 32];
  __shared__ bf16 Bs[128 * 32];
  const int tid = threadIdx.x;
  const int w = tid >> 6, l = tid & 63, g = l >> 4, c = l & 15;
  const int wr = w >> 1, wc = w & 1;
  // XCD-aware chunked remap (perf heuristic only; bijective since total%8==0)
  int lin = blockIdx.y * gridDim.x + blockIdx.x;
  int chunk = (gridDim.x * gridDim.y) >> 3;
  int nl = (lin & 7) * chunk + (lin >> 3);
  const int row0 = (nl % gridDim.x) * 128, col0 = (nl / gridDim.x) * 128;
  f32x4 acc[4][4] = {};

  for (int k0 = 0; k0 < K; k0 += 32) {
#pragma unroll
    for (int it = 0; it < 2; ++it) {
      int idx = it * 256 + tid;
      int r = idx >> 2, cc = idx & 3;
      gload16(A  + (size_t)(row0 + r) * K + k0 + cc * 8, &As[idx * 8]);
      gload16(Bt + (size_t)(col0 + r) * K + k0 + cc * 8, &Bs[idx * 8]);
    }
    __syncthreads();
    bf16x8 af[4], bfr[4];
#pragma unroll
    for (int m = 0; m < 4; ++m)
      af[m] = *(const bf16x8*)&As[(wr * 64 + m * 16 + c) * 32 + g * 8];
#pragma unroll
    for (int n = 0; n < 4; ++n)
      bfr[n] = *(const bf16x8*)&Bs[(wc * 64 + n * 16 + c) * 32 + g * 8];
#pragma unroll
    for (int m = 0; m < 4; ++m)
#pragma unroll
      for (int n = 0; n < 4; ++n)
        acc[m][n] = __builtin_amdgcn_mfma_f32_16x16x32_bf16(af[m], bfr[n],
                                                            acc[m][n], 0, 0, 0);
    __syncthreads();
  }

#pragma unroll
  for (int m = 0; m < 4; ++m) {
    int row = row0 + wr * 64 + m * 16 + g * 4;
#pragma unroll
    for (int n = 0; n < 4; ++n) {
      int col = col0 + wc * 64 + n * 16 + c;
      float bv = bias[col];
#pragma unroll
      for (int r = 0; r < 4; ++r) {
        float v = acc[m][n][r] + bv;
        C[(size_t)(row + r) * N + col] = (OutT)v;
      }
    }
  }
}

// ---------------- flash attention v6: swapped QK^T, lane-local softmax -----
// 1024 blocks, one 64-row q-tile each; 4 waves x 16 q-rows (lane's q = qw0+c).
// S^T = mfma(K, Q): per lane q=c fixed, s = st*16+g*4+r -> softmax row is
// lane-local: 2 shuffles instead of 32; P trip = 4x ds_write_b64 + 2x b128.
// PV: O^T = mfma(V^T, P). 2-buffer KV pipeline, 40KB LDS, 1 barrier/tile.
// mask: valid iff s <= q && !(s % 3 == 1 && s >= 4)
__global__ __launch_bounds__(256, 4) void k_attn(const bf16* __restrict__ qkv,
                                                 const bf16* __restrict__ vt,
                                                 bf16* __restrict__ att) {
  const int idx = blockIdx.x;
  const int slot = idx >> 8, j = idx & 255;
  const int r8 = j >> 5, bh = j & 31;
  const int b = bh >> 4, h = bh & 15;
  int qt;
  switch (slot) {
    case 0: qt = r8;       break;
    case 1: qt = 31 - r8;  break;
    case 2: qt = r8 + 8;   break;
    default: qt = 23 - r8; break;
  }

  const int tid = threadIdx.x;
  const int w = tid >> 6, l = tid & 63, g = l >> 4, c = l & 15;
  const int qw0 = qt * 64 + w * 16;
  const int nt = qt + 1;

  __shared__ bf16 Ks[2][64 * 64];    // [s][d] swizzled 128B rows (8KB each)
  __shared__ bf16 Vs[2][64 * 64];    // [d][s] swizzled 128B rows
  __shared__ bf16 Plds[4][16 * 64];  // per-wave [q][s] swizzled (2KB each)

  const bf16* kg = qkv + (size_t)(b * 2048) * 3072 + 1024 + h * 64;
  const bf16* vg = vt + (size_t)(b * 16 + h) * 64 * 2048;

  auto stage = [&](int buf, int t) {
    int s0 = t * 64;
#pragma unroll
    for (int it = 0; it < 2; ++it) {
      int ch = it * 256 + tid;
      int rr = ch >> 3, jj = (ch & 7) ^ (rr & 7);
      gload16(kg + (size_t)(s0 + rr) * 3072 + jj * 8, &Ks[buf][ch * 8]);
      gload16(vg + (size_t)rr * 2048 + s0 + jj * 8, &Vs[buf][ch * 8]);
    }
  };

  // Q B-frag: B[k=g*8+j][col=c] = Q[qw0+c][k]; pre-scaled by 0.125
  const bf16* qb = qkv + (size_t)(b * 2048 + qw0 + c) * 3072 + h * 64 + g * 8;
  bf16x8 qf0 = *(const bf16x8*)qb;
  bf16x8 qf1 = *(const bf16x8*)(qb + 32);
#pragma unroll
  for (int jq = 0; jq < 8; ++jq) {
    qf0[jq] = (bf16)((float)qf0[jq] * 0.125f);
    qf1[jq] = (bf16)((float)qf1[jq] * 0.125f);
  }

  // col-mask bitmasks: s = t*64 + off, off = st*16+g*4+r; s%3 = (t+off)%3
  // bit (st*4+r) set => masked (for t%3 = 0/1/2, assuming s>=4)
  unsigned cmA = 0, cmB = 0, cmC = 0;
#pragma unroll
  for (int st = 0; st < 4; ++st)
#pragma unroll
    for (int r = 0; r < 4; ++r) {
      int off = st * 16 + g * 4 + r;
      unsigned bit = 1u << (st * 4 + r);
      if (off % 3 == 1) cmA |= bit;
      if ((off + 1) % 3 == 1) cmB |= bit;
      if ((off + 2) % 3 == 1) cmC |= bit;
    }
  // t==0 exception: s=off<4 never masked (only off=1 qualifies via %3)
  unsigned cmA0 = cmA & ~((g == 0) ? 2u : 0u);

  f32x4 o[4] = {};
  float mrow = -1e30f, ell = 0.f;
  const int qq = qw0 + c;

  stage(0, 0);

  int cur = 0, tm = 0;
#pragma unroll 1
  for (int t = 0; t < nt; ++t) {
    asm volatile("s_waitcnt vmcnt(0)" ::: "memory");
    __builtin_amdgcn_sched_barrier(0);
    __builtin_amdgcn_s_barrier();       // stage(t) visible to all waves;
    __builtin_amdgcn_sched_barrier(0);  // all waves done with tile t-1

    if (t + 1 < nt) stage(cur ^ 1, t + 1);

    // ---- S^T = K Q^T : A = K rows (st*16+c), B = Q regs ----
    f32x4 ss[4] = {};
#pragma unroll
    for (int st = 0; st < 4; ++st) {
      bf16x8 ka  = *(const bf16x8*)swz(&Ks[cur][0], st * 16 + c, g * 16);
      bf16x8 kb2 = *(const bf16x8*)swz(&Ks[cur][0], st * 16 + c, 64 + g * 16);
      ss[st] = __builtin_amdgcn_mfma_f32_16x16x32_bf16(ka,  qf0, ss[st], 0, 0, 0);
      ss[st] = __builtin_amdgcn_mfma_f32_16x16x32_bf16(kb2, qf1, ss[st], 0, 0, 0);
    }

    // ---- mask: lane q=qq fixed; s = t*64 + st*16 + g*4 + r ----
    unsigned cm = (tm == 0) ? ((t == 0) ? cmA0 : cmA) : ((tm == 1) ? cmB : cmC);
    const bool diag = (t == qt);
    float mloc = -1e30f;
#pragma unroll
    for (int st = 0; st < 4; ++st)
#pragma unroll
      for (int r = 0; r < 4; ++r) {
        bool colm = (cm >> (st * 4 + r)) & 1u;
        bool ok = !colm;
        if (diag) {
          int s = t * 64 + st * 16 + g * 4 + r;
          ok = ok && (s <= qq);
        }
        float v = ok ? ss[st][r] : -1e30f;
        ss[st][r] = v;
        mloc = fmaxf(mloc, v);
      }
    // cross-lane reduce over the 4 g-groups only
    mloc = fmaxf(mloc, __shfl_xor(mloc, 16));
    mloc = fmaxf(mloc, __shfl_xor(mloc, 32));

    float mn = fmaxf(mrow, mloc);
    float al = __expf(mrow - mn);
    mrow = mn;
    float rsum = 0.f;
#pragma unroll
    for (int st = 0; st < 4; ++st) {
      float p0 = __expf(ss[st][0] - mn);
      float p1 = __expf(ss[st][1] - mn);
      float p2 = __expf(ss[st][2] - mn);
      float p3 = __expf(ss[st][3] - mn);
      rsum += (p0 + p1) + (p2 + p3);
      bf16x4 pk = {(bf16)p0, (bf16)p1, (bf16)p2, (bf16)p3};
      *(bf16x4*)swz(&Plds[w][0], c, st * 32 + g * 8) = pk;
    }
    rsum += __shfl_xor(rsum, 16);
    rsum += __shfl_xor(rsum, 32);
    ell = ell * al + rsum;
#pragma unroll
    for (int dc = 0; dc < 4; ++dc)
#pragma unroll
      for (int r = 0; r < 4; ++r) o[dc][r] *= al;

    // wave-private P cross-lane round trip (rule #18 fence pair)
    asm volatile("s_waitcnt lgkmcnt(0)" ::: "memory");
    __builtin_amdgcn_sched_barrier(0);

    // ---- O^T += V^T P : A = V^T rows (dc*16+c), B = P[q=c][s chunk] ----
#pragma unroll
    for (int kk = 0; kk < 2; ++kk) {
      bf16x8 pf = *(const bf16x8*)swz(&Plds[w][0], c, kk * 64 + g * 16);
#pragma unroll
      for (int dc = 0; dc < 4; ++dc) {
        bf16x8 vf = *(const bf16x8*)swz(&Vs[cur][0], dc * 16 + c, kk * 64 + g * 16);
        o[dc] = __builtin_amdgcn_mfma_f32_16x16x32_bf16(vf, pf, o[dc], 0, 0, 0);
      }
    }

    cur ^= 1;
    tm = (tm == 2) ? 0 : tm + 1;
  }

  // ---- epilogue: O^T (lane q=c, d=dc*16+g*4+r) -> LDS transpose -> b128 ---
  float inv = 1.f / ell;
#pragma unroll
  for (int dc = 0; dc < 4; ++dc) {
    bf16x4 ok4 = {(bf16)(o[dc][0] * inv), (bf16)(o[dc][1] * inv),
                  (bf16)(o[dc][2] * inv), (bf16)(o[dc][3] * inv)};
    *(bf16x4*)swz(&Plds[w][0], c, dc * 32 + g * 8) = ok4;  // [q=c][d]
  }
  asm volatile("s_waitcnt lgkmcnt(0)" ::: "memory");
  __builtin_amdgcn_sched_barrier(0);
#pragma unroll
  for (int p = 0; p < 2; ++p) {
    int row = p * 8 + (l >> 3);  // q-local 0..15
    bf16x8 vrow = *(const bf16x8*)swz(&Plds[w][0], row, (l & 7) * 16);
    *(bf16x8*)&att[(size_t)(b * 2048 + qt * 64 + w * 16 + row) * 1024 +
                   h * 64 + (l & 7) * 8] = vrow;
  }
}

// ---------------- launcher ----------------
extern "C" void kernel_launch(void* const* d_in, const int* in_sizes, int n_in,
                              void* d_out, int out_size, void* d_ws, size_t ws_size,
                              hipStream_t stream) {
  const float* x  = (const float*)d_in[0];
  const float* Wq = (const float*)d_in[1];
  const float* bq = (const float*)d_in[2];
  const float* Wk = (const float*)d_in[3];
  const float* bk = (const float*)d_in[4];
  const float* Wv = (const float*)d_in[5];
  const float* bv = (const float*)d_in[6];
  const float* Wp = (const float*)d_in[7];
  const float* bp = (const float*)d_in[8];
  float* out = (float*)d_out;

  char* ws = (char*)d_ws;
  const size_t MB = 1024 * 1024;
  bf16*  xb    = (bf16*)(ws);             // 8 MB [4096][1024]; reused as att
  bf16*  wqkvT = (bf16*)(ws + 8 * MB);    // 6 MB [3072][1024]
  bf16*  wpT   = (bf16*)(ws + 14 * MB);   // 2 MB [1024][1024]
  float* bcat  = (float*)(ws + 16 * MB);  // 12 KB
  bf16*  qkv   = (bf16*)(ws + 17 * MB);   // 24 MB [4096][3072]
  bf16*  vtr   = (bf16*)(ws + 41 * MB);   // 8 MB [2][16][64][2048]
  bf16*  att   = xb;                      // alias: xb dead after QKV GEMM

  k_cvt_bf16<<<2048, 256, 0, stream>>>(x, xb, 524288);
  k_wt<<<512, 256, 0, stream>>>(Wq, wqkvT);
  k_wt<<<512, 256, 0, stream>>>(Wk, wqkvT + 1024 * 1024);
  k_wt<<<512, 256, 0, stream>>>(Wv, wqkvT + 2 * 1024 * 1024);
  k_wt<<<512, 256, 0, stream>>>(Wp, wpT);
  k_bcat<<<12, 256, 0, stream>>>(bq, bk, bv, bcat);

  k_gemm_bt<bf16><<<dim3(32, 24), 256, 0, stream>>>(xb, wqkvT, bcat, qkv, 1024, 3072);
  k_transpose_v<<<2048, 256, 0, stream>>>(qkv, vtr);
  k_attn<<<1024, 256, 0, stream>>>(qkv, vtr, att);
  k_gemm_bt<float><<<dim3(32, 8), 256, 0, stream>>>(att, wpT, bp, out, 1024, 1024);
}

// Round 7
// 127.135 us; speedup vs baseline: 1.4138x; 1.1530x over previous
//
#include <hip/hip_runtime.h>

#define AS_GLOBAL __attribute__((address_space(1)))
#define AS_LDS    __attribute__((address_space(3)))

typedef __bf16 bf16;
typedef __bf16 bf16x4 __attribute__((ext_vector_type(4)));
typedef __bf16 bf16x8 __attribute__((ext_vector_type(8)));
typedef float  f32x4  __attribute__((ext_vector_type(4)));
typedef unsigned short u16x8 __attribute__((ext_vector_type(8)));

__device__ __forceinline__ void gload16(const void* g, void* l) {
  __builtin_amdgcn_global_load_lds((const AS_GLOBAL unsigned int*)g,
                                   (AS_LDS unsigned int*)l, 16, 0, 0);
}

// swizzled LDS address for a [R][128B] row-major tile:
// stored_byte = row*128 + (bytecol ^ ((row&7)<<4))
__device__ __forceinline__ void* swz(void* base, int row, int bytecol) {
  return (char*)base + row * 128 + (bytecol ^ ((row & 7) << 4));
}

// compacted-column helpers: kept columns are s with !(s%3==1 && s>=4).
// kept count in [0,X): X - max(0,(X-2)/3)  (trunc-div ok for X>=1)
__device__ __forceinline__ int keptcnt(int X) { return X - ((X - 2) < 0 ? 0 : (X - 2) / 3); }
// compact index -> original s (valid for ci>=2; ci<2 -> s=ci, caller handles)
__device__ __forceinline__ int ci2s(int ci) {
  return 3 * ((ci - 2) >> 1) + 2 + ((ci - 2) & 1);
}
__device__ __forceinline__ int ci2s_full(int ci) {
  return ci < 2 ? ci : ci2s(ci);
}

// ---------------- prep kernels ----------------

__global__ __launch_bounds__(256) void k_cvt_bf16(const float* __restrict__ x,
                                                  bf16* __restrict__ o, int n8) {
  int i = blockIdx.x * blockDim.x + threadIdx.x;
  if (i >= n8) return;
  const float4* p = (const float4*)(x + (size_t)i * 8);
  float4 a = p[0], b = p[1];
  bf16x8 v;
  v[0] = (bf16)a.x; v[1] = (bf16)a.y; v[2] = (bf16)a.z; v[3] = (bf16)a.w;
  v[4] = (bf16)b.x; v[5] = (bf16)b.y; v[6] = (bf16)b.z; v[7] = (bf16)b.w;
  *(bf16x8*)(o + (size_t)i * 8) = v;
}

// W [K=1024][N=1024] fp32 (in,out) -> WT [N][K] bf16
__global__ __launch_bounds__(256) void k_wt(const float* __restrict__ W,
                                            bf16* __restrict__ WT) {
  int lin = blockIdx.x * blockDim.x + threadIdx.x;
  int n  = lin & 1023;
  int kc = lin >> 10;
  bf16x8 v;
#pragma unroll
  for (int j = 0; j < 8; ++j) v[j] = (bf16)W[(size_t)(kc * 8 + j) * 1024 + n];
  *(bf16x8*)&WT[(size_t)n * 1024 + kc * 8] = v;
}

__global__ __launch_bounds__(256) void k_bcat(const float* __restrict__ bq,
                                              const float* __restrict__ bk,
                                              const float* __restrict__ bv,
                                              float* __restrict__ bc) {
  int i = blockIdx.x * blockDim.x + threadIdx.x;
  if (i < 1024) bc[i] = bq[i];
  else if (i < 2048) bc[i] = bk[i - 1024];
  else if (i < 3072) bc[i] = bv[i - 2048];
}

// K rows gathered by compact index: Kc[bh][1408][64]; zero-fill padding.
__global__ __launch_bounds__(256) void k_compact_k(const bf16* __restrict__ qkv,
                                                   bf16* __restrict__ kc) {
  int blk = blockIdx.x;                 // 32 bh * 44 rowchunks = 1408
  int bh = blk / 44, rc = blk % 44;
  int b = bh >> 4, h = bh & 15;
  int rr = threadIdx.x >> 3, ch = threadIdx.x & 7;
  int ci = rc * 32 + rr;
  int s = ci2s_full(ci);
  bf16x8 v = {};
  if (s < 2048)
    v = *(const bf16x8*)&qkv[(size_t)(b * 2048 + s) * 3072 + 1024 + h * 64 + ch * 8];
  *(bf16x8*)&kc[((size_t)bh * 1408 + ci) * 64 + ch * 8] = v;
}

// V gathered + transposed: Vc[bh][64][1408]; u32-packed LDS transpose.
__global__ __launch_bounds__(256) void k_compact_v(const bf16* __restrict__ qkv,
                                                   bf16* __restrict__ vc) {
  __shared__ unsigned L[32 * 65];       // [p=ci/2][d] u32, pitch 65 (bank-friendly)
  int blk = blockIdx.x;                 // 32 bh * 22 cichunks = 704
  int bh = blk / 22, cc = blk % 22;
  int b = bh >> 4, h = bh & 15;
  int ci0 = cc * 64;
  int tid = threadIdx.x;
  int p = tid >> 3, d0 = (tid & 7) * 8;
  int s0 = ci2s_full(ci0 + 2 * p), s1 = ci2s_full(ci0 + 2 * p + 1);
  u16x8 e = {}, od = {};
  if (s0 < 2048)
    e = *(const u16x8*)&qkv[(size_t)(b * 2048 + s0) * 3072 + 2048 + h * 64 + d0];
  if (s1 < 2048)
    od = *(const u16x8*)&qkv[(size_t)(b * 2048 + s1) * 3072 + 2048 + h * 64 + d0];
#pragma unroll
  for (int k2 = 0; k2 < 8; ++k2)
    L[p * 65 + d0 + k2] = (unsigned)e[k2] | ((unsigned)od[k2] << 16);
  __syncthreads();
#pragma unroll
  for (int it = 0; it < 2; ++it) {
    int d = it * 32 + (tid >> 3), jg = tid & 7;
    unsigned q4[4];
#pragma unroll
    for (int jj = 0; jj < 4; ++jj) q4[jj] = L[(jg * 4 + jj) * 65 + d];
    *(uint4*)&vc[((size_t)bh * 64 + d) * 1408 + ci0 + jg * 8] = *(uint4*)q4;
  }
}

// ---------------- GEMM: C[M,N] = A[M,K] @ Bt[N,K]^T + bias ----------------
template <typename OutT>
__global__ __launch_bounds__(256) void k_gemm_bt(const bf16* __restrict__ A,
                                                 const bf16* __restrict__ Bt,
                                                 const float* __restrict__ bias,
                                                 OutT* __restrict__ C,
                                                 int K, int N) {
  __shared__ bf16 As[128 * 32];
  __shared__ bf16 Bs[128 * 32];
  const int tid = threadIdx.x;
  const int w = tid >> 6, l = tid & 63, g = l >> 4, c = l & 15;
  const int wr = w >> 1, wc = w & 1;
  // XCD-aware chunked remap (perf heuristic only; bijective since total%8==0)
  int lin = blockIdx.y * gridDim.x + blockIdx.x;
  int chunk = (gridDim.x * gridDim.y) >> 3;
  int nl = (lin & 7) * chunk + (lin >> 3);
  const int row0 = (nl % gridDim.x) * 128, col0 = (nl / gridDim.x) * 128;
  f32x4 acc[4][4] = {};

  for (int k0 = 0; k0 < K; k0 += 32) {
#pragma unroll
    for (int it = 0; it < 2; ++it) {
      int idx = it * 256 + tid;
      int r = idx >> 2, cc = idx & 3;
      gload16(A  + (size_t)(row0 + r) * K + k0 + cc * 8, &As[idx * 8]);
      gload16(Bt + (size_t)(col0 + r) * K + k0 + cc * 8, &Bs[idx * 8]);
    }
    __syncthreads();
    bf16x8 af[4], bfr[4];
#pragma unroll
    for (int m = 0; m < 4; ++m)
      af[m] = *(const bf16x8*)&As[(wr * 64 + m * 16 + c) * 32 + g * 8];
#pragma unroll
    for (int n = 0; n < 4; ++n)
      bfr[n] = *(const bf16x8*)&Bs[(wc * 64 + n * 16 + c) * 32 + g * 8];
#pragma unroll
    for (int m = 0; m < 4; ++m)
#pragma unroll
      for (int n = 0; n < 4; ++n)
        acc[m][n] = __builtin_amdgcn_mfma_f32_16x16x32_bf16(af[m], bfr[n],
                                                            acc[m][n], 0, 0, 0);
    __syncthreads();
  }

#pragma unroll
  for (int m = 0; m < 4; ++m) {
    int row = row0 + wr * 64 + m * 16 + g * 4;
#pragma unroll
    for (int n = 0; n < 4; ++n) {
      int col = col0 + wc * 64 + n * 16 + c;
      float bv = bias[col];
#pragma unroll
      for (int r = 0; r < 4; ++r) {
        float v = acc[m][n][r] + bv;
        C[(size_t)(row + r) * N + col] = (OutT)v;
      }
    }
  }
}

// ---------------- flash attention v7: compacted K/V -----------------------
// Masked columns (s%3==1, s>=4) are DELETED from K/V (compact index ci,
// 1366 kept + pad to 1408). Clean tiles need no masking at all; only the
// <=2 tiles crossing the causal boundary compute s_orig(ci) and test s<=q.
// Swapped QK^T (S^T = K Q^T), lane-local softmax. 2-buf pipeline, 40KB LDS.
__global__ __launch_bounds__(256, 4) void k_attn(const bf16* __restrict__ qkv,
                                                 const bf16* __restrict__ kc,
                                                 const bf16* __restrict__ vc,
                                                 bf16* __restrict__ att) {
  const int idx = blockIdx.x;
  const int slot = idx >> 8, j = idx & 255;
  const int r8 = j >> 5, bh = j & 31;
  const int b = bh >> 4, h = bh & 15;
  int qt;
  switch (slot) {
    case 0: qt = r8;       break;
    case 1: qt = 31 - r8;  break;
    case 2: qt = r8 + 8;   break;
    default: qt = 23 - r8; break;
  }

  const int tid = threadIdx.x;
  const int w = tid >> 6, l = tid & 63, g = l >> 4, c = l & 15;
  const int qw0 = qt * 64 + w * 16;
  const int qq = qw0 + c;

  // tile counts in compact space
  const int nt = (keptcnt(qt * 64 + 64) + 63) >> 6;      // tiles to process
  const int tmaskw = keptcnt(qw0 + 1) >> 6;              // first tile needing mask

  __shared__ bf16 Ks[2][64 * 64];    // [ci][d] swizzled 128B rows (8KB each)
  __shared__ bf16 Vs[2][64 * 64];    // [d][ci] swizzled 128B rows
  __shared__ bf16 Plds[4][16 * 64];  // per-wave [q][s] swizzled (2KB each)

  const bf16* kgc = kc + (size_t)bh * 1408 * 64;
  const bf16* vgc = vc + (size_t)bh * 64 * 1408;

  auto stage = [&](int buf, int t) {
    int s0 = t * 64;
#pragma unroll
    for (int it = 0; it < 2; ++it) {
      int ch = it * 256 + tid;
      int rr = ch >> 3, jj = (ch & 7) ^ (rr & 7);
      gload16(kgc + (size_t)(s0 + rr) * 64 + jj * 8, &Ks[buf][ch * 8]);
      gload16(vgc + (size_t)rr * 1408 + s0 + jj * 8, &Vs[buf][ch * 8]);
    }
  };

  // Q B-frag: B[k=g*8+j][col=c] = Q[qw0+c][k]; pre-scaled by 0.125
  const bf16* qb = qkv + (size_t)(b * 2048 + qq) * 3072 + h * 64 + g * 8;
  bf16x8 qf0 = *(const bf16x8*)qb;
  bf16x8 qf1 = *(const bf16x8*)(qb + 32);
#pragma unroll
  for (int jq = 0; jq < 8; ++jq) {
    qf0[jq] = (bf16)((float)qf0[jq] * 0.125f);
    qf1[jq] = (bf16)((float)qf1[jq] * 0.125f);
  }

  f32x4 o[4] = {};
  float mrow = -1e30f, ell = 0.f;

  stage(0, 0);

  int cur = 0;
#pragma unroll 1
  for (int t = 0; t < nt; ++t) {
    asm volatile("s_waitcnt vmcnt(0)" ::: "memory");
    __builtin_amdgcn_sched_barrier(0);
    __builtin_amdgcn_s_barrier();       // stage(t) visible to all waves;
    __builtin_amdgcn_sched_barrier(0);  // all waves done with tile t-1

    if (t + 1 < nt) stage(cur ^ 1, t + 1);

    // ---- S^T = K Q^T : A = K rows (st*16+c), B = Q regs ----
    f32x4 ss[4] = {};
#pragma unroll
    for (int st = 0; st < 4; ++st) {
      bf16x8 ka  = *(const bf16x8*)swz(&Ks[cur][0], st * 16 + c, g * 16);
      bf16x8 kb2 = *(const bf16x8*)swz(&Ks[cur][0], st * 16 + c, 64 + g * 16);
      ss[st] = __builtin_amdgcn_mfma_f32_16x16x32_bf16(ka,  qf0, ss[st], 0, 0, 0);
      ss[st] = __builtin_amdgcn_mfma_f32_16x16x32_bf16(kb2, qf1, ss[st], 0, 0, 0);
    }

    // ---- causal mask only on boundary tiles (lane q=qq fixed) ----
    float mloc = -1e30f;
    if (t >= tmaskw) {
#pragma unroll
      for (int st = 0; st < 4; ++st)
#pragma unroll
        for (int r = 0; r < 4; ++r) {
          int ci = t * 64 + st * 16 + g * 4 + r;
          int s = ci2s(ci);
          if (t == 0) s = (ci < 2) ? ci : s;   // only tile 0 holds ci<2
          float v = (s <= qq) ? ss[st][r] : -1e30f;
          ss[st][r] = v;
          mloc = fmaxf(mloc, v);
        }
    } else {
#pragma unroll
      for (int st = 0; st < 4; ++st)
#pragma unroll
        for (int r = 0; r < 4; ++r) mloc = fmaxf(mloc, ss[st][r]);
    }
    // cross-lane reduce over the 4 g-groups only
    mloc = fmaxf(mloc, __shfl_xor(mloc, 16));
    mloc = fmaxf(mloc, __shfl_xor(mloc, 32));

    float mn = fmaxf(mrow, mloc);
    float al = __expf(mrow - mn);
    mrow = mn;
    float rsum = 0.f;
#pragma unroll
    for (int st = 0; st < 4; ++st) {
      float p0 = __expf(ss[st][0] - mn);
      float p1 = __expf(ss[st][1] - mn);
      float p2 = __expf(ss[st][2] - mn);
      float p3 = __expf(ss[st][3] - mn);
      rsum += (p0 + p1) + (p2 + p3);
      bf16x4 pk = {(bf16)p0, (bf16)p1, (bf16)p2, (bf16)p3};
      *(bf16x4*)swz(&Plds[w][0], c, st * 32 + g * 8) = pk;
    }
    rsum += __shfl_xor(rsum, 16);
    rsum += __shfl_xor(rsum, 32);
    ell = ell * al + rsum;
#pragma unroll
    for (int dc = 0; dc < 4; ++dc)
#pragma unroll
      for (int r = 0; r < 4; ++r) o[dc][r] *= al;

    // wave-private P cross-lane round trip (rule #18 fence pair)
    asm volatile("s_waitcnt lgkmcnt(0)" ::: "memory");
    __builtin_amdgcn_sched_barrier(0);

    // ---- O^T += V^T P : A = V^T rows (dc*16+c), B = P[q=c][s chunk] ----
#pragma unroll
    for (int kk = 0; kk < 2; ++kk) {
      bf16x8 pf = *(const bf16x8*)swz(&Plds[w][0], c, kk * 64 + g * 16);
#pragma unroll
      for (int dc = 0; dc < 4; ++dc) {
        bf16x8 vf = *(const bf16x8*)swz(&Vs[cur][0], dc * 16 + c, kk * 64 + g * 16);
        o[dc] = __builtin_amdgcn_mfma_f32_16x16x32_bf16(vf, pf, o[dc], 0, 0, 0);
      }
    }

    cur ^= 1;
  }

  // ---- epilogue: O^T (lane q=c, d=dc*16+g*4+r) -> LDS transpose -> b128 ---
  float inv = 1.f / ell;
#pragma unroll
  for (int dc = 0; dc < 4; ++dc) {
    bf16x4 ok4 = {(bf16)(o[dc][0] * inv), (bf16)(o[dc][1] * inv),
                  (bf16)(o[dc][2] * inv), (bf16)(o[dc][3] * inv)};
    *(bf16x4*)swz(&Plds[w][0], c, dc * 32 + g * 8) = ok4;  // [q=c][d]
  }
  asm volatile("s_waitcnt lgkmcnt(0)" ::: "memory");
  __builtin_amdgcn_sched_barrier(0);
#pragma unroll
  for (int p = 0; p < 2; ++p) {
    int row = p * 8 + (l >> 3);  // q-local 0..15
    bf16x8 vrow = *(const bf16x8*)swz(&Plds[w][0], row, (l & 7) * 16);
    *(bf16x8*)&att[(size_t)(b * 2048 + qt * 64 + w * 16 + row) * 1024 +
                   h * 64 + (l & 7) * 8] = vrow;
  }
}

// ---------------- launcher ----------------
extern "C" void kernel_launch(void* const* d_in, const int* in_sizes, int n_in,
                              void* d_out, int out_size, void* d_ws, size_t ws_size,
                              hipStream_t stream) {
  const float* x  = (const float*)d_in[0];
  const float* Wq = (const float*)d_in[1];
  const float* bq = (const float*)d_in[2];
  const float* Wk = (const float*)d_in[3];
  const float* bk = (const float*)d_in[4];
  const float* Wv = (const float*)d_in[5];
  const float* bv = (const float*)d_in[6];
  const float* Wp = (const float*)d_in[7];
  const float* bp = (const float*)d_in[8];
  float* out = (float*)d_out;

  char* ws = (char*)d_ws;
  const size_t MB = 1024 * 1024;
  bf16*  xb    = (bf16*)(ws);             // 8 MB [4096][1024]; reused as att
  bf16*  wqkvT = (bf16*)(ws + 8 * MB);    // 6 MB; dead after QKV GEMM
  bf16*  wpT   = (bf16*)(ws + 14 * MB);   // 2 MB [1024][1024]
  float* bcat  = (float*)(ws + 16 * MB);  // 12 KB
  bf16*  qkv   = (bf16*)(ws + 17 * MB);   // 24 MB [4096][3072]
  bf16*  kcb   = wqkvT;                   // 5.5 MB [32][1408][64] (over dead wqkvT)
  bf16*  vcb   = (bf16*)(ws + 41 * MB);   // 5.5 MB [32][64][1408]
  bf16*  att   = xb;                      // alias: xb dead after QKV GEMM

  k_cvt_bf16<<<2048, 256, 0, stream>>>(x, xb, 524288);
  k_wt<<<512, 256, 0, stream>>>(Wq, wqkvT);
  k_wt<<<512, 256, 0, stream>>>(Wk, wqkvT + 1024 * 1024);
  k_wt<<<512, 256, 0, stream>>>(Wv, wqkvT + 2 * 1024 * 1024);
  k_wt<<<512, 256, 0, stream>>>(Wp, wpT);
  k_bcat<<<12, 256, 0, stream>>>(bq, bk, bv, bcat);

  k_gemm_bt<bf16><<<dim3(32, 24), 256, 0, stream>>>(xb, wqkvT, bcat, qkv, 1024, 3072);
  k_compact_k<<<1408, 256, 0, stream>>>(qkv, kcb);
  k_compact_v<<<704, 256, 0, stream>>>(qkv, vcb);
  k_attn<<<1024, 256, 0, stream>>>(qkv, kcb, vcb, att);
  k_gemm_bt<float><<<dim3(32, 8), 256, 0, stream>>>(att, wpT, bp, out, 1024, 1024);
}

// Round 8
// 119.143 us; speedup vs baseline: 1.5086x; 1.0671x over previous
//
#include <hip/hip_runtime.h>

#define AS_GLOBAL __attribute__((address_space(1)))
#define AS_LDS    __attribute__((address_space(3)))

typedef __bf16 bf16;
typedef __bf16 bf16x4 __attribute__((ext_vector_type(4)));
typedef __bf16 bf16x8 __attribute__((ext_vector_type(8)));
typedef float  f32x4  __attribute__((ext_vector_type(4)));
typedef unsigned short u16x8 __attribute__((ext_vector_type(8)));

__device__ __forceinline__ void gload16(const void* g, void* l) {
  __builtin_amdgcn_global_load_lds((const AS_GLOBAL unsigned int*)g,
                                   (AS_LDS unsigned int*)l, 16, 0, 0);
}

// swizzled LDS address for a [R][128B] row-major tile:
// stored_byte = row*128 + (bytecol ^ ((row&7)<<4))
__device__ __forceinline__ void* swz(void* base, int row, int bytecol) {
  return (char*)base + row * 128 + (bytecol ^ ((row & 7) << 4));
}

// compacted-column helpers: kept columns are s with !(s%3==1 && s>=4).
// kept count in [0,X): X - max(0,(X-2)/3)  (trunc-div ok for X>=1)
__device__ __forceinline__ int keptcnt(int X) { return X - ((X - 2) < 0 ? 0 : (X - 2) / 3); }
// compact index -> original s (valid for ci>=2; ci<2 -> s=ci, caller handles)
__device__ __forceinline__ int ci2s(int ci) {
  return 3 * ((ci - 2) >> 1) + 2 + ((ci - 2) & 1);
}
__device__ __forceinline__ int ci2s_full(int ci) {
  return ci < 2 ? ci : ci2s(ci);
}

// ---------------- prep kernels ----------------

__global__ __launch_bounds__(256) void k_cvt_bf16(const float* __restrict__ x,
                                                  bf16* __restrict__ o, int n8) {
  int i = blockIdx.x * blockDim.x + threadIdx.x;
  if (i >= n8) return;
  const float4* p = (const float4*)(x + (size_t)i * 8);
  float4 a = p[0], b = p[1];
  bf16x8 v;
  v[0] = (bf16)a.x; v[1] = (bf16)a.y; v[2] = (bf16)a.z; v[3] = (bf16)a.w;
  v[4] = (bf16)b.x; v[5] = (bf16)b.y; v[6] = (bf16)b.z; v[7] = (bf16)b.w;
  *(bf16x8*)(o + (size_t)i * 8) = v;
}

// W [K=1024][N=1024] fp32 (in,out) -> WT [N][K] bf16
__global__ __launch_bounds__(256) void k_wt(const float* __restrict__ W,
                                            bf16* __restrict__ WT) {
  int lin = blockIdx.x * blockDim.x + threadIdx.x;
  int n  = lin & 1023;
  int kc = lin >> 10;
  bf16x8 v;
#pragma unroll
  for (int j = 0; j < 8; ++j) v[j] = (bf16)W[(size_t)(kc * 8 + j) * 1024 + n];
  *(bf16x8*)&WT[(size_t)n * 1024 + kc * 8] = v;
}

__global__ __launch_bounds__(256) void k_bcat(const float* __restrict__ bq,
                                              const float* __restrict__ bk,
                                              const float* __restrict__ bv,
                                              float* __restrict__ bc) {
  int i = blockIdx.x * blockDim.x + threadIdx.x;
  if (i < 1024) bc[i] = bq[i];
  else if (i < 2048) bc[i] = bk[i - 1024];
  else if (i < 3072) bc[i] = bv[i - 2048];
}

// K rows gathered by compact index: Kc[bh][1408][64]; zero-fill padding.
__global__ __launch_bounds__(256) void k_compact_k(const bf16* __restrict__ qkv,
                                                   bf16* __restrict__ kc) {
  int blk = blockIdx.x;                 // 32 bh * 44 rowchunks = 1408
  int bh = blk / 44, rc = blk % 44;
  int b = bh >> 4, h = bh & 15;
  int rr = threadIdx.x >> 3, ch = threadIdx.x & 7;
  int ci = rc * 32 + rr;
  int s = ci2s_full(ci);
  bf16x8 v = {};
  if (s < 2048)
    v = *(const bf16x8*)&qkv[(size_t)(b * 2048 + s) * 3072 + 1024 + h * 64 + ch * 8];
  *(bf16x8*)&kc[((size_t)bh * 1408 + ci) * 64 + ch * 8] = v;
}

// V gathered + transposed: Vc[bh][64][1408]; u32-packed LDS transpose.
__global__ __launch_bounds__(256) void k_compact_v(const bf16* __restrict__ qkv,
                                                   bf16* __restrict__ vc) {
  __shared__ unsigned L[32 * 65];       // [p=ci/2][d] u32, pitch 65 (bank-friendly)
  int blk = blockIdx.x;                 // 32 bh * 22 cichunks = 704
  int bh = blk / 22, cc = blk % 22;
  int b = bh >> 4, h = bh & 15;
  int ci0 = cc * 64;
  int tid = threadIdx.x;
  int p = tid >> 3, d0 = (tid & 7) * 8;
  int s0 = ci2s_full(ci0 + 2 * p), s1 = ci2s_full(ci0 + 2 * p + 1);
  u16x8 e = {}, od = {};
  if (s0 < 2048)
    e = *(const u16x8*)&qkv[(size_t)(b * 2048 + s0) * 3072 + 2048 + h * 64 + d0];
  if (s1 < 2048)
    od = *(const u16x8*)&qkv[(size_t)(b * 2048 + s1) * 3072 + 2048 + h * 64 + d0];
#pragma unroll
  for (int k2 = 0; k2 < 8; ++k2)
    L[p * 65 + d0 + k2] = (unsigned)e[k2] | ((unsigned)od[k2] << 16);
  __syncthreads();
#pragma unroll
  for (int it = 0; it < 2; ++it) {
    int d = it * 32 + (tid >> 3), jg = tid & 7;
    unsigned q4[4];
#pragma unroll
    for (int jj = 0; jj < 4; ++jj) q4[jj] = L[(jg * 4 + jj) * 65 + d];
    *(uint4*)&vc[((size_t)bh * 64 + d) * 1408 + ci0 + jg * 8] = *(uint4*)q4;
  }
}

// ---------------- GEMM: C[M,N] = A[M,K] @ Bt[N,K]^T + bias ----------------
// v2: (a) granule XOR-swizzle (jj = cc ^ ((r>>1)&3)) kills the 8-way LDS
// read conflict (quarter-lane banks become 2-way = free, m136);
// (b) double-buffered 2-phase prefetch: stage(t+1) issued before compute(t),
// raw s_barrier + vmcnt(0) per K-step (T3-minimum) so loads fly under MFMA.
template <typename OutT>
__global__ __launch_bounds__(256) void k_gemm_bt(const bf16* __restrict__ A,
                                                 const bf16* __restrict__ Bt,
                                                 const float* __restrict__ bias,
                                                 OutT* __restrict__ C,
                                                 int K, int N) {
  __shared__ bf16 As[2][128 * 32];
  __shared__ bf16 Bs[2][128 * 32];
  const int tid = threadIdx.x;
  const int w = tid >> 6, l = tid & 63, g = l >> 4, c = l & 15;
  const int wr = w >> 1, wc = w & 1;
  // XCD-aware chunked remap (perf heuristic only; bijective since total%8==0)
  int lin = blockIdx.y * gridDim.x + blockIdx.x;
  int chunk = (gridDim.x * gridDim.y) >> 3;
  int nl = (lin & 7) * chunk + (lin >> 3);
  const int row0 = (nl % gridDim.x) * 128, col0 = (nl / gridDim.x) * 128;
  f32x4 acc[4][4] = {};

  // stage one 128x32 A-tile + B-tile at k0 into buf; source granule
  // pre-swizzled (involution: read side XORs the same ((row>>1)&3)).
  auto stage = [&](int buf, int k0) {
#pragma unroll
    for (int it = 0; it < 2; ++it) {
      int idx = it * 256 + tid;
      int r = idx >> 2, cc = idx & 3;
      int jj = cc ^ ((r >> 1) & 3);
      gload16(A  + (size_t)(row0 + r) * K + k0 + jj * 8, &As[buf][idx * 8]);
      gload16(Bt + (size_t)(col0 + r) * K + k0 + jj * 8, &Bs[buf][idx * 8]);
    }
  };

  stage(0, 0);
  int cur = 0;
#pragma unroll 1
  for (int k0 = 0; k0 < K; k0 += 32) {
    asm volatile("s_waitcnt vmcnt(0)" ::: "memory");
    __builtin_amdgcn_sched_barrier(0);
    __builtin_amdgcn_s_barrier();       // stage(k0) visible to all waves;
    __builtin_amdgcn_sched_barrier(0);  // all waves done with buf cur^1

    if (k0 + 32 < K) stage(cur ^ 1, k0 + 32);

    bf16x8 af[4], bfr[4];
#pragma unroll
    for (int m = 0; m < 4; ++m) {
      int row = wr * 64 + m * 16 + c;
      af[m] = *(const bf16x8*)&As[cur][row * 32 + (g ^ ((row >> 1) & 3)) * 8];
    }
#pragma unroll
    for (int n = 0; n < 4; ++n) {
      int row = wc * 64 + n * 16 + c;
      bfr[n] = *(const bf16x8*)&Bs[cur][row * 32 + (g ^ ((row >> 1) & 3)) * 8];
    }
#pragma unroll
    for (int m = 0; m < 4; ++m)
#pragma unroll
      for (int n = 0; n < 4; ++n)
        acc[m][n] = __builtin_amdgcn_mfma_f32_16x16x32_bf16(af[m], bfr[n],
                                                            acc[m][n], 0, 0, 0);
    cur ^= 1;
  }

#pragma unroll
  for (int m = 0; m < 4; ++m) {
    int row = row0 + wr * 64 + m * 16 + g * 4;
#pragma unroll
    for (int n = 0; n < 4; ++n) {
      int col = col0 + wc * 64 + n * 16 + c;
      float bv = bias[col];
#pragma unroll
      for (int r = 0; r < 4; ++r) {
        float v = acc[m][n][r] + bv;
        C[(size_t)(row + r) * N + col] = (OutT)v;
      }
    }
  }
}

// ---------------- flash attention v7: compacted K/V -----------------------
// Masked columns (s%3==1, s>=4) are DELETED from K/V (compact index ci,
// 1366 kept + pad to 1408). Clean tiles need no masking at all; only the
// <=2 tiles crossing the causal boundary compute s_orig(ci) and test s<=q.
// Swapped QK^T (S^T = K Q^T), lane-local softmax. 2-buf pipeline, 40KB LDS.
__global__ __launch_bounds__(256, 4) void k_attn(const bf16* __restrict__ qkv,
                                                 const bf16* __restrict__ kc,
                                                 const bf16* __restrict__ vc,
                                                 bf16* __restrict__ att) {
  const int idx = blockIdx.x;
  const int slot = idx >> 8, j = idx & 255;
  const int r8 = j >> 5, bh = j & 31;
  const int b = bh >> 4, h = bh & 15;
  int qt;
  switch (slot) {
    case 0: qt = r8;       break;
    case 1: qt = 31 - r8;  break;
    case 2: qt = r8 + 8;   break;
    default: qt = 23 - r8; break;
  }

  const int tid = threadIdx.x;
  const int w = tid >> 6, l = tid & 63, g = l >> 4, c = l & 15;
  const int qw0 = qt * 64 + w * 16;
  const int qq = qw0 + c;

  // tile counts in compact space
  const int nt = (keptcnt(qt * 64 + 64) + 63) >> 6;      // tiles to process
  const int tmaskw = keptcnt(qw0 + 1) >> 6;              // first tile needing mask

  __shared__ bf16 Ks[2][64 * 64];    // [ci][d] swizzled 128B rows (8KB each)
  __shared__ bf16 Vs[2][64 * 64];    // [d][ci] swizzled 128B rows
  __shared__ bf16 Plds[4][16 * 64];  // per-wave [q][s] swizzled (2KB each)

  const bf16* kgc = kc + (size_t)bh * 1408 * 64;
  const bf16* vgc = vc + (size_t)bh * 64 * 1408;

  auto stage = [&](int buf, int t) {
    int s0 = t * 64;
#pragma unroll
    for (int it = 0; it < 2; ++it) {
      int ch = it * 256 + tid;
      int rr = ch >> 3, jj = (ch & 7) ^ (rr & 7);
      gload16(kgc + (size_t)(s0 + rr) * 64 + jj * 8, &Ks[buf][ch * 8]);
      gload16(vgc + (size_t)rr * 1408 + s0 + jj * 8, &Vs[buf][ch * 8]);
    }
  };

  // Q B-frag: B[k=g*8+j][col=c] = Q[qw0+c][k]; pre-scaled by 0.125
  const bf16* qb = qkv + (size_t)(b * 2048 + qq) * 3072 + h * 64 + g * 8;
  bf16x8 qf0 = *(const bf16x8*)qb;
  bf16x8 qf1 = *(const bf16x8*)(qb + 32);
#pragma unroll
  for (int jq = 0; jq < 8; ++jq) {
    qf0[jq] = (bf16)((float)qf0[jq] * 0.125f);
    qf1[jq] = (bf16)((float)qf1[jq] * 0.125f);
  }

  f32x4 o[4] = {};
  float mrow = -1e30f, ell = 0.f;

  stage(0, 0);

  int cur = 0;
#pragma unroll 1
  for (int t = 0; t < nt; ++t) {
    asm volatile("s_waitcnt vmcnt(0)" ::: "memory");
    __builtin_amdgcn_sched_barrier(0);
    __builtin_amdgcn_s_barrier();       // stage(t) visible to all waves;
    __builtin_amdgcn_sched_barrier(0);  // all waves done with tile t-1

    if (t + 1 < nt) stage(cur ^ 1, t + 1);

    // ---- S^T = K Q^T : A = K rows (st*16+c), B = Q regs ----
    f32x4 ss[4] = {};
#pragma unroll
    for (int st = 0; st < 4; ++st) {
      bf16x8 ka  = *(const bf16x8*)swz(&Ks[cur][0], st * 16 + c, g * 16);
      bf16x8 kb2 = *(const bf16x8*)swz(&Ks[cur][0], st * 16 + c, 64 + g * 16);
      ss[st] = __builtin_amdgcn_mfma_f32_16x16x32_bf16(ka,  qf0, ss[st], 0, 0, 0);
      ss[st] = __builtin_amdgcn_mfma_f32_16x16x32_bf16(kb2, qf1, ss[st], 0, 0, 0);
    }

    // ---- causal mask only on boundary tiles (lane q=qq fixed) ----
    float mloc = -1e30f;
    if (t >= tmaskw) {
#pragma unroll
      for (int st = 0; st < 4; ++st)
#pragma unroll
        for (int r = 0; r < 4; ++r) {
          int ci = t * 64 + st * 16 + g * 4 + r;
          int s = ci2s(ci);
          if (t == 0) s = (ci < 2) ? ci : s;   // only tile 0 holds ci<2
          float v = (s <= qq) ? ss[st][r] : -1e30f;
          ss[st][r] = v;
          mloc = fmaxf(mloc, v);
        }
    } else {
#pragma unroll
      for (int st = 0; st < 4; ++st)
#pragma unroll
        for (int r = 0; r < 4; ++r) mloc = fmaxf(mloc, ss[st][r]);
    }
    // cross-lane reduce over the 4 g-groups only
    mloc = fmaxf(mloc, __shfl_xor(mloc, 16));
    mloc = fmaxf(mloc, __shfl_xor(mloc, 32));

    float mn = fmaxf(mrow, mloc);
    float al = __expf(mrow - mn);
    mrow = mn;
    float rsum = 0.f;
#pragma unroll
    for (int st = 0; st < 4; ++st) {
      float p0 = __expf(ss[st][0] - mn);
      float p1 = __expf(ss[st][1] - mn);
      float p2 = __expf(ss[st][2] - mn);
      float p3 = __expf(ss[st][3] - mn);
      rsum += (p0 + p1) + (p2 + p3);
      bf16x4 pk = {(bf16)p0, (bf16)p1, (bf16)p2, (bf16)p3};
      *(bf16x4*)swz(&Plds[w][0], c, st * 32 + g * 8) = pk;
    }
    rsum += __shfl_xor(rsum, 16);
    rsum += __shfl_xor(rsum, 32);
    ell = ell * al + rsum;
#pragma unroll
    for (int dc = 0; dc < 4; ++dc)
#pragma unroll
      for (int r = 0; r < 4; ++r) o[dc][r] *= al;

    // wave-private P cross-lane round trip (rule #18 fence pair)
    asm volatile("s_waitcnt lgkmcnt(0)" ::: "memory");
    __builtin_amdgcn_sched_barrier(0);

    // ---- O^T += V^T P : A = V^T rows (dc*16+c), B = P[q=c][s chunk] ----
#pragma unroll
    for (int kk = 0; kk < 2; ++kk) {
      bf16x8 pf = *(const bf16x8*)swz(&Plds[w][0], c, kk * 64 + g * 16);
#pragma unroll
      for (int dc = 0; dc < 4; ++dc) {
        bf16x8 vf = *(const bf16x8*)swz(&Vs[cur][0], dc * 16 + c, kk * 64 + g * 16);
        o[dc] = __builtin_amdgcn_mfma_f32_16x16x32_bf16(vf, pf, o[dc], 0, 0, 0);
      }
    }

    cur ^= 1;
  }

  // ---- epilogue: O^T (lane q=c, d=dc*16+g*4+r) -> LDS transpose -> b128 ---
  float inv = 1.f / ell;
#pragma unroll
  for (int dc = 0; dc < 4; ++dc) {
    bf16x4 ok4 = {(bf16)(o[dc][0] * inv), (bf16)(o[dc][1] * inv),
                  (bf16)(o[dc][2] * inv), (bf16)(o[dc][3] * inv)};
    *(bf16x4*)swz(&Plds[w][0], c, dc * 32 + g * 8) = ok4;  // [q=c][d]
  }
  asm volatile("s_waitcnt lgkmcnt(0)" ::: "memory");
  __builtin_amdgcn_sched_barrier(0);
#pragma unroll
  for (int p = 0; p < 2; ++p) {
    int row = p * 8 + (l >> 3);  // q-local 0..15
    bf16x8 vrow = *(const bf16x8*)swz(&Plds[w][0], row, (l & 7) * 16);
    *(bf16x8*)&att[(size_t)(b * 2048 + qt * 64 + w * 16 + row) * 1024 +
                   h * 64 + (l & 7) * 8] = vrow;
  }
}

// ---------------- launcher ----------------
extern "C" void kernel_launch(void* const* d_in, const int* in_sizes, int n_in,
                              void* d_out, int out_size, void* d_ws, size_t ws_size,
                              hipStream_t stream) {
  const float* x  = (const float*)d_in[0];
  const float* Wq = (const float*)d_in[1];
  const float* bq = (const float*)d_in[2];
  const float* Wk = (const float*)d_in[3];
  const float* bk = (const float*)d_in[4];
  const float* Wv = (const float*)d_in[5];
  const float* bv = (const float*)d_in[6];
  const float* Wp = (const float*)d_in[7];
  const float* bp = (const float*)d_in[8];
  float* out = (float*)d_out;

  char* ws = (char*)d_ws;
  const size_t MB = 1024 * 1024;
  bf16*  xb    = (bf16*)(ws);             // 8 MB [4096][1024]; reused as att
  bf16*  wqkvT = (bf16*)(ws + 8 * MB);    // 6 MB; dead after QKV GEMM
  bf16*  wpT   = (bf16*)(ws + 14 * MB);   // 2 MB [1024][1024]
  float* bcat  = (float*)(ws + 16 * MB);  // 12 KB
  bf16*  qkv   = (bf16*)(ws + 17 * MB);   // 24 MB [4096][3072]
  bf16*  kcb   = wqkvT;                   // 5.5 MB [32][1408][64] (over dead wqkvT)
  bf16*  vcb   = (bf16*)(ws + 41 * MB);   // 5.5 MB [32][64][1408]
  bf16*  att   = xb;                      // alias: xb dead after QKV GEMM

  k_cvt_bf16<<<2048, 256, 0, stream>>>(x, xb, 524288);
  k_wt<<<512, 256, 0, stream>>>(Wq, wqkvT);
  k_wt<<<512, 256, 0, stream>>>(Wk, wqkvT + 1024 * 1024);
  k_wt<<<512, 256, 0, stream>>>(Wv, wqkvT + 2 * 1024 * 1024);
  k_wt<<<512, 256, 0, stream>>>(Wp, wpT);
  k_bcat<<<12, 256, 0, stream>>>(bq, bk, bv, bcat);

  k_gemm_bt<bf16><<<dim3(32, 24), 256, 0, stream>>>(xb, wqkvT, bcat, qkv, 1024, 3072);
  k_compact_k<<<1408, 256, 0, stream>>>(qkv, kcb);
  k_compact_v<<<704, 256, 0, stream>>>(qkv, vcb);
  k_attn<<<1024, 256, 0, stream>>>(qkv, kcb, vcb, att);
  k_gemm_bt<float><<<dim3(32, 8), 256, 0, stream>>>(att, wpT, bp, out, 1024, 1024);
}